// Round 11
// baseline (101.263 us; speedup 1.0000x reference)
//
#include <hip/hip_runtime.h>
#include <math.h>

// ListwiseSmoothINDCGKLoss: bs x ll (16384 x 2048) fp32 scores + graded labels
// -> scalar sum(1 - ndcg@10).
//
// Round-11 structure: WAVE PAIR PER ROW. 512-thread blocks (8 waves), wave
// pair (2j,2j+1) owns row j; each wave covers half the row (EPT=16). Per-k:
// local DPP partial reduction -> lane63 writes float2(se,sle) to LDS ->
// ONE __syncthreads -> both waves combine the pair's two slots. Ping-pong
// LDS buffers keep it at 1 barrier/k.
// Why: round 9 was latency-bound (VALUBusy 55%, occ 2.3 waves/SIMD) on the
// serial per-k chain. Round 10 proved a second independent chain fixes issue
// efficiency but was INVALID (it covered only half of each row; absmax 64).
// The pair split gives: live set w16+q16+e16+misc ~ 60 VGPR -> <=64
// occupancy bin (8 waves/SIMD, vs 68 -> 4), 2x waves (32/SIMD), and half the
// per-wave elementwise latency -- correctly.
//
// Carried techniques:
//  - packed VOP3P fp32 (v_pk_add/mul/fma) for all elementwise phases.
//  - VOLATILE asm pin of exponentials (non-volatile pin gets duplicated with
//    a remat'd exp2 -- round 8).
//  - scale-invariant softmax: M_k = min(range,118)*0.9^k bound, no per-k max.
//  - NO local arrays (rounds 2-3: scratch allocas -> GB spill traffic).
//  - IDCG closed-form from packed label histogram (labels are ints 0..4).
//  - DPP wave64 reductions (row_shr 1,2,4,8 + row_bcast 15,31), rcp not div.

typedef float v2f __attribute__((ext_vector_type(2)));

constexpr int LL      = 2048;
constexpr int THREADS = 512;  // 8 waves; wave pair (2j,2j+1) owns row j
constexpr int RPB     = 4;    // rows per block
constexpr int KTOP    = 10;
constexpr float ALPHA  = 10.0f;
constexpr float EPSF   = 1e-10f;
constexpr float LOG2E  = 1.44269504088896340736f;
constexpr float MCLAMP = 118.0f;

// 1 / log2(k+2), k = 0..9 (constexpr + unroll-constant index => immediates)
__device__ constexpr float INVDEN[KTOP] = {
    1.0f,                 0.6309297535714574f, 0.5f,                0.43067655807339306f,
    0.38685280723454163f, 0.356207187108022f,  0.3333333333333333f, 0.31546487678572877f,
    0.30102999566398114f, 0.2890648263178878f};

// ---- VOP3P packed fp32 helpers ----
__device__ __forceinline__ v2f pk_add(v2f a, v2f b) {
    v2f d; asm("v_pk_add_f32 %0, %1, %2" : "=v"(d) : "v"(a), "v"(b)); return d;
}
__device__ __forceinline__ v2f pk_mul(v2f a, v2f b) {
    v2f d; asm("v_pk_mul_f32 %0, %1, %2" : "=v"(d) : "v"(a), "v"(b)); return d;
}
__device__ __forceinline__ v2f pk_fma(v2f a, v2f b, v2f c) {
    v2f d; asm("v_pk_fma_f32 %0, %1, %2, %3" : "=v"(d) : "v"(a), "v"(b), "v"(c)); return d;
}

// ---- DPP wave64 reductions (result lands in lane 63) ----
template <int CTRL>
__device__ __forceinline__ float dpp_addf(float v) {
    return v + __int_as_float(__builtin_amdgcn_update_dpp(
                   0, __float_as_int(v), CTRL, 0xF, 0xF, false));
}
template <int CTRL>
__device__ __forceinline__ float dpp_minf(float v) {
    return fminf(v, __int_as_float(__builtin_amdgcn_update_dpp(
                        0x7F800000, __float_as_int(v), CTRL, 0xF, 0xF, false)));
}
template <int CTRL>
__device__ __forceinline__ float dpp_maxf(float v) {
    return fmaxf(v, __int_as_float(__builtin_amdgcn_update_dpp(
                        (int)0xFF800000, __float_as_int(v), CTRL, 0xF, 0xF, false)));
}
template <int CTRL>
__device__ __forceinline__ int dpp_addi(int v) {
    return v + __builtin_amdgcn_update_dpp(0, v, CTRL, 0xF, 0xF, false);
}

// row_shr:1,2,4,8 then row_bcast:15, row_bcast:31
#define WAVE_RED(OP, v)                                                     \
    v = OP<0x111>(v); v = OP<0x112>(v); v = OP<0x114>(v); v = OP<0x118>(v); \
    v = OP<0x142>(v); v = OP<0x143>(v);

// chunk expander: 4 chunks x 4 scalars = 16 elements per lane (half row)
#define CH(F) F(0) F(1) F(2) F(3)

__global__ __launch_bounds__(THREADS) void ndcg_loss_kernel(
    const float* __restrict__ s, const float* __restrict__ label,
    float* __restrict__ ws, float* __restrict__ out, int mode) {
    __shared__ float2 red[2][8];  // ping-pong (se,sle) per wave
    __shared__ float2 mmx[8];     // (min,max) per wave
    __shared__ int4   hst[8];     // packed hist per wave

    const int    lane = threadIdx.x & 63;
    const int    wave = threadIdx.x >> 6;   // 0..7
    const int    half = wave & 1;           // which half-row this wave owns
    const int    mate = wave ^ 1;
    const size_t row  = (size_t)blockIdx.x * RPB + (wave >> 1);

    const float4* sp = (const float4*)(s + row * (size_t)LL);
    const float4* lp = (const float4*)(label + row * (size_t)LL);
    const int     b0 = half * 256;  // float4 offset of this half-row

#define LOADS(c) const float4 sA##c = sp[b0 + (c) * 64 + lane];
    CH(LOADS)
#define LOADL(c) const float4 qA##c = lp[b0 + (c) * 64 + lane];
    CH(LOADL)

    // ---- local min/max over half-row + DPP ----
    float mn = sA0.x, mx = sA0.x;
#define MM(c)                                                                \
    mn = fminf(mn, fminf(fminf(sA##c.x, sA##c.y), fminf(sA##c.z, sA##c.w))); \
    mx = fmaxf(mx, fmaxf(fmaxf(sA##c.x, sA##c.y), fmaxf(sA##c.z, sA##c.w)));
    CH(MM)
    WAVE_RED(dpp_minf, mn)
    WAVE_RED(dpp_maxf, mx)

    // ---- packed label histogram: hA = c0|c1<<16, hB = c2|c3<<16, hC = c4 ----
    int hA = 0, hB = 0, hC = 0;
#define H1(qv)                                  \
    {                                           \
        const int li = (int)(qv);               \
        hA += (li == 0) + ((li == 1) << 16);    \
        hB += (li == 2) + ((li == 3) << 16);    \
        hC += (li == 4);                        \
    }
#define HC(c) H1(qA##c.x) H1(qA##c.y) H1(qA##c.z) H1(qA##c.w)
    CH(HC)
    WAVE_RED(dpp_addi, hA)
    WAVE_RED(dpp_addi, hB)
    WAVE_RED(dpp_addi, hC)

    if (lane == 63) {
        mmx[wave] = make_float2(mn, mx);
        hst[wave] = make_int4(hA, hB, hC, 0);
    }
    __syncthreads();
    {
        const float2 a = mmx[wave], b = mmx[mate];
        mn = fminf(a.x, b.x);
        mx = fmaxf(a.y, b.y);
        const int4 ha = hst[wave], hb = hst[mate];
        hA = ha.x + hb.x;
        hB = ha.y + hb.y;
        hC = ha.z + hb.z;
    }

    const int n4 = hC;
    const int n3 = n4 + (hB >> 16);
    const int n2 = n3 + (hB & 0xFFFF);
    const int n1 = n2 + (hA >> 16);
    float idcg = EPSF;
#pragma unroll
    for (int slot = 0; slot < KTOP; ++slot) {
        const int v = (slot < n4) + (slot < n3) + (slot < n2) + (slot < n1);
        idcg = fmaf((float)(1 << v), INVDEN[slot], idcg);
    }

    // ---- packed persistent state: w = z*prod (init z), q labels ----
    const float Cc = ALPHA * LOG2E;
#define WD(c)                                                           \
    v2f wL##c = {(sA##c.x - mn) * Cc, (sA##c.y - mn) * Cc};             \
    v2f wH##c = {(sA##c.z - mn) * Cc, (sA##c.w - mn) * Cc};             \
    const v2f qL##c = {qA##c.x, qA##c.y};                               \
    const v2f qH##c = {qA##c.z, qA##c.w};
    CH(WD)
    float M   = fminf((mx - mn) * Cc, MCLAMP);
    float dcg = EPSF;

#pragma unroll
    for (int k = 0; k < KTOP; ++k) {
        const v2f nM2 = {-M, -M};
#define EDECL(c) v2f eL##c, eH##c;
        CH(EDECL)
        // e = exp2(w - M); volatile pin -> no deletion, no duplication
#define ED(c)                                                       \
    {                                                               \
        const v2f dL = pk_add(wL##c, nM2), dH = pk_add(wH##c, nM2); \
        eL##c.x = __builtin_amdgcn_exp2f(dL.x);                     \
        eL##c.y = __builtin_amdgcn_exp2f(dL.y);                     \
        eH##c.x = __builtin_amdgcn_exp2f(dH.x);                     \
        eH##c.y = __builtin_amdgcn_exp2f(dH.y);                     \
        asm volatile("" : "+v"(eL##c), "+v"(eH##c));                \
    }
        CH(ED)

        v2f accA = {0.0f, 0.0f}, accB = {0.0f, 0.0f};
#define AC(c)                                      \
    accA = pk_add(accA, pk_add(eL##c, eH##c));     \
    accB = pk_fma(qL##c, eL##c,                    \
                  pk_fma(qH##c, eH##c, accB));
        CH(AC)
        float se  = accA.x + accA.y;
        float sle = accB.x + accB.y;
        WAVE_RED(dpp_addf, se)
        WAVE_RED(dpp_addf, sle)

        if (lane == 63) red[k & 1][wave] = make_float2(se, sle);
        __syncthreads();
        {
            const float2 a = red[k & 1][wave], b = red[k & 1][mate];
            se  = a.x + b.x;
            sle = a.y + b.y;
        }

        const float inv = __builtin_amdgcn_rcpf(se);
        dcg = fmaf(__builtin_amdgcn_exp2f(sle * inv), INVDEN[k], dcg);

        // w' = w * (0.9 - e*inv)   [prod update folded into w]
        const v2f niv2 = {-inv, -inv};
        const v2f c09  = {0.9f, 0.9f};
#define UP(c)                                        \
    wL##c = pk_mul(wL##c, pk_fma(eL##c, niv2, c09)); \
    wH##c = pk_mul(wH##c, pk_fma(eH##c, niv2, c09));
        CH(UP)
        M *= 0.9f;
    }

    if (half == 0 && lane == 0) {
        const float loss = 1.0f - dcg / idcg;
        if (mode) atomicAdd(out, loss);
        else      ws[row] = loss;
    }
}

__global__ __launch_bounds__(256) void reduce_sum_kernel(
    const float* __restrict__ w, float* __restrict__ out, int n4) {
    __shared__ float sb[4];
    float acc = 0.0f;
    const float4* w4 = (const float4*)w;
    for (int i = threadIdx.x; i < n4; i += 256) {
        const float4 v = w4[i];
        acc += (v.x + v.y) + (v.z + v.w);
    }
#pragma unroll
    for (int o = 32; o; o >>= 1) acc += __shfl_xor(acc, o, 64);
    if ((threadIdx.x & 63) == 0) sb[threadIdx.x >> 6] = acc;
    __syncthreads();
    if (threadIdx.x == 0) out[0] = (sb[0] + sb[1]) + (sb[2] + sb[3]);
}

__global__ void zero_out_kernel(float* out) { out[0] = 0.0f; }

extern "C" void kernel_launch(void* const* d_in, const int* in_sizes, int n_in,
                              void* d_out, int out_size, void* d_ws,
                              size_t ws_size, hipStream_t stream) {
    const float* s     = (const float*)d_in[0];
    const float* label = (const float*)d_in[1];
    float*       out   = (float*)d_out;
    const int    bs    = in_sizes[0] / LL;

    if ((bs % RPB) == 0 && ws_size >= (size_t)bs * sizeof(float)) {
        float* w = (float*)d_ws;
        ndcg_loss_kernel<<<bs / RPB, THREADS, 0, stream>>>(s, label, w, nullptr, 0);
        reduce_sum_kernel<<<1, 256, 0, stream>>>(w, out, bs / 4);
    } else {
        zero_out_kernel<<<1, 1, 0, stream>>>(out);
        ndcg_loss_kernel<<<bs / RPB, THREADS, 0, stream>>>(s, label, nullptr, out, 1);
    }
}

// Round 16
// 92.512 us; speedup vs baseline: 1.0946x; 1.0946x over previous
//
#include <hip/hip_runtime.h>
#include <math.h>

// ListwiseSmoothINDCGKLoss: bs x ll (16384 x 2048) fp32 scores + graded labels
// -> scalar sum(1 - ndcg@10).
//
// Round-16: ONE WAVE OWNS TWO FULL ROWS, built ONLY from proven-correct
// components. Elimination table across rounds:
//   r9/r11: volatile-pinned persistent e, no remat  -> CORRECT
//   r12/r14/r15: UPD-phase exp2 remat (3 label variants) -> NaN x3
// => the remat construct miscompiles; abandoned permanently. This kernel is
// r9's wave body literally duplicated per row (pinned e reused in UPD),
// f32 v2f labels, all-f32 math.
//
// Register budget: w(64)+q(64)+pinned e(64)+misc ~= 210-230 VGPR. With
// __launch_bounds__(256,1) the cap is >=256 (r6/r7 calibration: cap ~=
// 256/min_waves), so no spills; 129-256 VGPR bin = 2 waves/SIMD theoretical,
// matching r9's MEASURED residency (~2.3) -> real TLP unchanged, per-wave
// independent chains doubled (mechanism r10 measured at 53 us).
//
// Carried: packed VOP3P fp32 elementwise (r9-r11); volatile pin of e right
// after exp2 (non-volatile pin gets duplicated+remat'd, r8); scale-invariant
// softmax M_k = min(range,118)*0.9^k (no per-k max); NO local arrays; IDCG
// closed form from packed histogram; DPP wave64 reductions; rcp not div.

typedef float v2f __attribute__((ext_vector_type(2)));

constexpr int LL      = 2048;
constexpr int THREADS = 256;  // 4 waves; each wave owns 2 rows
constexpr int RPB     = 8;    // rows per block
constexpr int KTOP    = 10;
constexpr float ALPHA  = 10.0f;
constexpr float EPSF   = 1e-10f;
constexpr float LOG2E  = 1.44269504088896340736f;
constexpr float MCLAMP = 118.0f;

__device__ constexpr float INVDEN[KTOP] = {
    1.0f,                 0.6309297535714574f, 0.5f,                0.43067655807339306f,
    0.38685280723454163f, 0.356207187108022f,  0.3333333333333333f, 0.31546487678572877f,
    0.30102999566398114f, 0.2890648263178878f};

// ---- VOP3P packed fp32 helpers (validated rounds 9-11) ----
__device__ __forceinline__ v2f pk_add(v2f a, v2f b) {
    v2f d; asm("v_pk_add_f32 %0, %1, %2" : "=v"(d) : "v"(a), "v"(b)); return d;
}
__device__ __forceinline__ v2f pk_mul(v2f a, v2f b) {
    v2f d; asm("v_pk_mul_f32 %0, %1, %2" : "=v"(d) : "v"(a), "v"(b)); return d;
}
__device__ __forceinline__ v2f pk_fma(v2f a, v2f b, v2f c) {
    v2f d; asm("v_pk_fma_f32 %0, %1, %2, %3" : "=v"(d) : "v"(a), "v"(b), "v"(c)); return d;
}

// ---- DPP wave64 reductions (result lands in lane 63) ----
template <int CTRL>
__device__ __forceinline__ float dpp_addf(float v) {
    return v + __int_as_float(__builtin_amdgcn_update_dpp(
                   0, __float_as_int(v), CTRL, 0xF, 0xF, false));
}
template <int CTRL>
__device__ __forceinline__ float dpp_minf(float v) {
    return fminf(v, __int_as_float(__builtin_amdgcn_update_dpp(
                        0x7F800000, __float_as_int(v), CTRL, 0xF, 0xF, false)));
}
template <int CTRL>
__device__ __forceinline__ float dpp_maxf(float v) {
    return fmaxf(v, __int_as_float(__builtin_amdgcn_update_dpp(
                        (int)0xFF800000, __float_as_int(v), CTRL, 0xF, 0xF, false)));
}
template <int CTRL>
__device__ __forceinline__ int dpp_addi(int v) {
    return v + __builtin_amdgcn_update_dpp(0, v, CTRL, 0xF, 0xF, false);
}

#define WAVE_RED(OP, v)                                                     \
    v = OP<0x111>(v); v = OP<0x112>(v); v = OP<0x114>(v); v = OP<0x118>(v); \
    v = OP<0x142>(v); v = OP<0x143>(v);

__device__ __forceinline__ float rl63f(float v) {
    return __int_as_float(__builtin_amdgcn_readlane(__float_as_int(v), 63));
}

__device__ __forceinline__ float idcg_from_hist(int hA, int hB, int hC) {
    const int n4 = hC;
    const int n3 = n4 + (hB >> 16);
    const int n2 = n3 + (hB & 0xFFFF);
    const int n1 = n2 + (hA >> 16);
    float idcg = EPSF;
#pragma unroll
    for (int slot = 0; slot < KTOP; ++slot) {
        const int v = (slot < n4) + (slot < n3) + (slot < n2) + (slot < n1);
        idcg = fmaf((float)(1 << v), INVDEN[slot], idcg);
    }
    return idcg;
}

// 8 chunks x 2 rows, row-interleaved to aid scheduling
#define FORALL(F) F(0,0) F(0,1) F(1,0) F(1,1) F(2,0) F(2,1) F(3,0) F(3,1) \
                  F(4,0) F(4,1) F(5,0) F(5,1) F(6,0) F(6,1) F(7,0) F(7,1)

__global__ __launch_bounds__(THREADS, 1) void ndcg_loss_kernel(
    const float* __restrict__ s, const float* __restrict__ label,
    float* __restrict__ ws, float* __restrict__ out, int mode) {
    const int    lane = threadIdx.x & 63;
    const int    wave = threadIdx.x >> 6;
    const size_t r0   = ((size_t)blockIdx.x * 4 + wave) * 2;

    const float4* sp0 = (const float4*)(s + r0 * (size_t)LL);
    const float4* sp1 = (const float4*)(s + (r0 + 1) * (size_t)LL);
    const float4* lp0 = (const float4*)(label + r0 * (size_t)LL);
    const float4* lp1 = (const float4*)(label + (r0 + 1) * (size_t)LL);

    // ---- score loads + min/max ----
#define LOADS(c, R) const float4 sA##c##_##R = sp##R[(c) * 64 + lane];
    FORALL(LOADS)
    float mn_0 = sA0_0.x, mx_0 = sA0_0.x;
    float mn_1 = sA0_1.x, mx_1 = sA0_1.x;
#define MM(c, R)                                                        \
    mn_##R = fminf(mn_##R, fminf(fminf(sA##c##_##R.x, sA##c##_##R.y),   \
                                 fminf(sA##c##_##R.z, sA##c##_##R.w))); \
    mx_##R = fmaxf(mx_##R, fmaxf(fmaxf(sA##c##_##R.x, sA##c##_##R.y),   \
                                 fmaxf(sA##c##_##R.z, sA##c##_##R.w)));
    FORALL(MM)
    WAVE_RED(dpp_minf, mn_0)
    WAVE_RED(dpp_maxf, mx_0)
    WAVE_RED(dpp_minf, mn_1)
    WAVE_RED(dpp_maxf, mx_1)
    mn_0 = rl63f(mn_0); mx_0 = rl63f(mx_0);
    mn_1 = rl63f(mn_1); mx_1 = rl63f(mx_1);

    // ---- label loads: histogram + f32 v2f storage ----
    int hA_0 = 0, hB_0 = 0, hC_0 = 0, hA_1 = 0, hB_1 = 0, hC_1 = 0;
#define QDECL(c, R) v2f qL##c##_##R, qH##c##_##R;
    FORALL(QDECL)
#define H1(qv, R)                                 \
    {                                             \
        const int li = (int)(qv);                 \
        hA_##R += (li == 0) + ((li == 1) << 16);  \
        hB_##R += (li == 2) + ((li == 3) << 16);  \
        hC_##R += (li == 4);                      \
    }
#define LQ(c, R)                                              \
    {                                                         \
        const float4 qv = lp##R[(c) * 64 + lane];             \
        H1(qv.x, R) H1(qv.y, R) H1(qv.z, R) H1(qv.w, R)       \
        qL##c##_##R.x = qv.x; qL##c##_##R.y = qv.y;           \
        qH##c##_##R.x = qv.z; qH##c##_##R.y = qv.w;           \
    }
    FORALL(LQ)
    WAVE_RED(dpp_addi, hA_0)
    WAVE_RED(dpp_addi, hB_0)
    WAVE_RED(dpp_addi, hC_0)
    WAVE_RED(dpp_addi, hA_1)
    WAVE_RED(dpp_addi, hB_1)
    WAVE_RED(dpp_addi, hC_1)
    const float idcg_0 = idcg_from_hist(__builtin_amdgcn_readlane(hA_0, 63),
                                        __builtin_amdgcn_readlane(hB_0, 63),
                                        __builtin_amdgcn_readlane(hC_0, 63));
    const float idcg_1 = idcg_from_hist(__builtin_amdgcn_readlane(hA_1, 63),
                                        __builtin_amdgcn_readlane(hB_1, 63),
                                        __builtin_amdgcn_readlane(hC_1, 63));

    // ---- persistent packed state: w = z*prod (init z) ----
    const float Cc = ALPHA * LOG2E;
#define WD(c, R)                                                                      \
    v2f wL##c##_##R = {(sA##c##_##R.x - mn_##R) * Cc, (sA##c##_##R.y - mn_##R) * Cc}; \
    v2f wH##c##_##R = {(sA##c##_##R.z - mn_##R) * Cc, (sA##c##_##R.w - mn_##R) * Cc};
    FORALL(WD)
    float M_0 = fminf((mx_0 - mn_0) * Cc, MCLAMP);
    float M_1 = fminf((mx_1 - mn_1) * Cc, MCLAMP);
    float dcg_0 = EPSF, dcg_1 = EPSF;

#pragma unroll
    for (int k = 0; k < KTOP; ++k) {
        const v2f nM2_0 = {-M_0, -M_0};
        const v2f nM2_1 = {-M_1, -M_1};

        // ---- ACC phase: e computed, VOLATILE-PINNED (r9/r11-proven),
        // reused in UPD. No remat anywhere. ----
#define EDECL(c, R) v2f eL##c##_##R, eH##c##_##R;
        FORALL(EDECL)
        v2f accA_0 = {0.0f, 0.0f}, accB_0 = {0.0f, 0.0f};
        v2f accA_1 = {0.0f, 0.0f}, accB_1 = {0.0f, 0.0f};
#define ACC(c, R)                                                       \
    {                                                                   \
        const v2f dL = pk_add(wL##c##_##R, nM2_##R);                    \
        const v2f dH = pk_add(wH##c##_##R, nM2_##R);                    \
        eL##c##_##R.x = __builtin_amdgcn_exp2f(dL.x);                   \
        eL##c##_##R.y = __builtin_amdgcn_exp2f(dL.y);                   \
        eH##c##_##R.x = __builtin_amdgcn_exp2f(dH.x);                   \
        eH##c##_##R.y = __builtin_amdgcn_exp2f(dH.y);                   \
        asm volatile("" : "+v"(eL##c##_##R), "+v"(eH##c##_##R));        \
        accA_##R = pk_add(accA_##R, pk_add(eL##c##_##R, eH##c##_##R));  \
        accB_##R = pk_fma(qL##c##_##R, eL##c##_##R,                     \
                          pk_fma(qH##c##_##R, eH##c##_##R, accB_##R));  \
    }
        FORALL(ACC)

        // ---- 4 independent DPP chains ----
        float se_0  = accA_0.x + accA_0.y, sle_0 = accB_0.x + accB_0.y;
        float se_1  = accA_1.x + accA_1.y, sle_1 = accB_1.x + accB_1.y;
        WAVE_RED(dpp_addf, se_0)
        WAVE_RED(dpp_addf, sle_0)
        WAVE_RED(dpp_addf, se_1)
        WAVE_RED(dpp_addf, sle_1)
        se_0 = rl63f(se_0); sle_0 = rl63f(sle_0);
        se_1 = rl63f(se_1); sle_1 = rl63f(sle_1);

        const float inv_0 = __builtin_amdgcn_rcpf(se_0);
        const float inv_1 = __builtin_amdgcn_rcpf(se_1);
        dcg_0 = fmaf(__builtin_amdgcn_exp2f(sle_0 * inv_0), INVDEN[k], dcg_0);
        dcg_1 = fmaf(__builtin_amdgcn_exp2f(sle_1 * inv_1), INVDEN[k], dcg_1);

        // ---- UPD phase: reuse pinned e (r9 pattern) ----
        const v2f niv2_0 = {-inv_0, -inv_0};
        const v2f niv2_1 = {-inv_1, -inv_1};
        const v2f c09    = {0.9f, 0.9f};
#define UPD(c, R)                                                              \
    wL##c##_##R = pk_mul(wL##c##_##R, pk_fma(eL##c##_##R, niv2_##R, c09));     \
    wH##c##_##R = pk_mul(wH##c##_##R, pk_fma(eH##c##_##R, niv2_##R, c09));
        FORALL(UPD)
        M_0 *= 0.9f;
        M_1 *= 0.9f;
    }

    if (lane == 0) {
        const float loss0 = 1.0f - dcg_0 / idcg_0;
        const float loss1 = 1.0f - dcg_1 / idcg_1;
        if (mode) {
            atomicAdd(out, loss0 + loss1);
        } else {
            ws[r0]     = loss0;
            ws[r0 + 1] = loss1;
        }
    }
}

__global__ __launch_bounds__(256) void reduce_sum_kernel(
    const float* __restrict__ w, float* __restrict__ out, int n4) {
    __shared__ float sb[4];
    float acc = 0.0f;
    const float4* w4 = (const float4*)w;
    for (int i = threadIdx.x; i < n4; i += 256) {
        const float4 v = w4[i];
        acc += (v.x + v.y) + (v.z + v.w);
    }
#pragma unroll
    for (int o = 32; o; o >>= 1) acc += __shfl_xor(acc, o, 64);
    if ((threadIdx.x & 63) == 0) sb[threadIdx.x >> 6] = acc;
    __syncthreads();
    if (threadIdx.x == 0) out[0] = (sb[0] + sb[1]) + (sb[2] + sb[3]);
}

__global__ void zero_out_kernel(float* out) { out[0] = 0.0f; }

extern "C" void kernel_launch(void* const* d_in, const int* in_sizes, int n_in,
                              void* d_out, int out_size, void* d_ws,
                              size_t ws_size, hipStream_t stream) {
    const float* s     = (const float*)d_in[0];
    const float* label = (const float*)d_in[1];
    float*       out   = (float*)d_out;
    const int    bs    = in_sizes[0] / LL;

    if ((bs % RPB) == 0 && ws_size >= (size_t)bs * sizeof(float)) {
        float* w = (float*)d_ws;
        ndcg_loss_kernel<<<bs / RPB, THREADS, 0, stream>>>(s, label, w, nullptr, 0);
        reduce_sum_kernel<<<1, 256, 0, stream>>>(w, out, bs / 4);
    } else {
        zero_out_kernel<<<1, 1, 0, stream>>>(out);
        ndcg_loss_kernel<<<bs / RPB, THREADS, 0, stream>>>(s, label, nullptr, out, 1);
    }
}

// Round 17
// 79.829 us; speedup vs baseline: 1.2685x; 1.1589x over previous
//
#include <hip/hip_runtime.h>
#include <math.h>

// ListwiseSmoothINDCGKLoss: bs x ll (16384 x 2048) fp32 scores + graded labels
// -> scalar sum(1 - ndcg@10).
//
// Round-17 = round-9 base (best valid: 75.4 us; 1 row/wave, EPT=32, zero
// LDS/barriers, DPP reductions, volatile-pinned e, packed VOP3P) with two
// latency-attacks:
//  (1) 1-WAVE BLOCKS (64 threads, 1 row/block): r9's measured residency was
//      ~9 waves/CU vs 28 permitted by VGPR -- all kernels cap at ~9-13
//      regardless of VGPR, suggesting block-granularity packing. The kernel
//      uses no LDS/barriers, so the 4-wave block was an artificial container.
//  (2) t-trick: w' = w*(0.9 - e*inv) rewritten as t=e*w, wm=0.9*w (computed
//      BEFORE inv arrives -> schedulable into the DPP chain's stall shadow),
//      then one pk_fma(t,-inv,wm) after the broadcast. Post-inv serial
//      segment halves (32 -> 16 ops). Algebraically identical (+-1 ulp).
//
// Permanently abandoned (r12/14/15 NaN x3): UPD-phase exp2 remat. 2-rows/
// wave abandoned (r10 invalid, r11 barrier-taxed, r16 AGPR-shuffle-taxed).
//
// Carried: packed VOP3P fp32 (r9-r11); volatile pin of e after exp2 (r8:
// non-volatile pins get duplicated+remat'd); scale-invariant softmax
// M_k = min(range,118)*0.9^k (no per-k max); NO local arrays (r2-r3);
// IDCG closed form from packed histogram; DPP wave64 reductions; rcp.

typedef float v2f __attribute__((ext_vector_type(2)));

constexpr int LL      = 2048;
constexpr int THREADS = 64;   // ONE wave per block; one row per block
constexpr int KTOP    = 10;
constexpr float ALPHA  = 10.0f;
constexpr float EPSF   = 1e-10f;
constexpr float LOG2E  = 1.44269504088896340736f;
constexpr float MCLAMP = 118.0f;

__device__ constexpr float INVDEN[KTOP] = {
    1.0f,                 0.6309297535714574f, 0.5f,                0.43067655807339306f,
    0.38685280723454163f, 0.356207187108022f,  0.3333333333333333f, 0.31546487678572877f,
    0.30102999566398114f, 0.2890648263178878f};

// ---- VOP3P packed fp32 helpers (validated rounds 9-11) ----
__device__ __forceinline__ v2f pk_add(v2f a, v2f b) {
    v2f d; asm("v_pk_add_f32 %0, %1, %2" : "=v"(d) : "v"(a), "v"(b)); return d;
}
__device__ __forceinline__ v2f pk_mul(v2f a, v2f b) {
    v2f d; asm("v_pk_mul_f32 %0, %1, %2" : "=v"(d) : "v"(a), "v"(b)); return d;
}
__device__ __forceinline__ v2f pk_fma(v2f a, v2f b, v2f c) {
    v2f d; asm("v_pk_fma_f32 %0, %1, %2, %3" : "=v"(d) : "v"(a), "v"(b), "v"(c)); return d;
}

// ---- DPP wave64 reductions (result lands in lane 63) ----
template <int CTRL>
__device__ __forceinline__ float dpp_addf(float v) {
    return v + __int_as_float(__builtin_amdgcn_update_dpp(
                   0, __float_as_int(v), CTRL, 0xF, 0xF, false));
}
template <int CTRL>
__device__ __forceinline__ float dpp_minf(float v) {
    return fminf(v, __int_as_float(__builtin_amdgcn_update_dpp(
                        0x7F800000, __float_as_int(v), CTRL, 0xF, 0xF, false)));
}
template <int CTRL>
__device__ __forceinline__ float dpp_maxf(float v) {
    return fmaxf(v, __int_as_float(__builtin_amdgcn_update_dpp(
                        (int)0xFF800000, __float_as_int(v), CTRL, 0xF, 0xF, false)));
}
template <int CTRL>
__device__ __forceinline__ int dpp_addi(int v) {
    return v + __builtin_amdgcn_update_dpp(0, v, CTRL, 0xF, 0xF, false);
}

// row_shr:1,2,4,8 then row_bcast:15, row_bcast:31
#define WAVE_RED(OP, v)                                                     \
    v = OP<0x111>(v); v = OP<0x112>(v); v = OP<0x114>(v); v = OP<0x118>(v); \
    v = OP<0x142>(v); v = OP<0x143>(v);

__device__ __forceinline__ float rl63f(float v) {
    return __int_as_float(__builtin_amdgcn_readlane(__float_as_int(v), 63));
}

// chunk expander: 8 chunks x 4 scalars = 32 elements per lane
#define CH(F) F(0) F(1) F(2) F(3) F(4) F(5) F(6) F(7)

__global__ __launch_bounds__(THREADS, 2) void ndcg_loss_kernel(
    const float* __restrict__ s, const float* __restrict__ label,
    float* __restrict__ ws, float* __restrict__ out, int mode) {
    const int    lane = threadIdx.x & 63;
    const size_t row  = blockIdx.x;

    const float4* sp = (const float4*)(s + row * (size_t)LL);
    const float4* lp = (const float4*)(label + row * (size_t)LL);

    // coalesced loads: chunk c = 1 KB contiguous (64 lanes x 16 B)
#define LOADS(c) const float4 sA##c = sp[(c) * 64 + lane];
    CH(LOADS)
#define LOADL(c) const float4 qA##c = lp[(c) * 64 + lane];
    CH(LOADL)

    // ---- row min / max ----
    float mn = sA0.x, mx = sA0.x;
#define MM(c)                                                                \
    mn = fminf(mn, fminf(fminf(sA##c.x, sA##c.y), fminf(sA##c.z, sA##c.w))); \
    mx = fmaxf(mx, fmaxf(fmaxf(sA##c.x, sA##c.y), fmaxf(sA##c.z, sA##c.w)));
    CH(MM)
    WAVE_RED(dpp_minf, mn)
    WAVE_RED(dpp_maxf, mx)
    mn = rl63f(mn);
    mx = rl63f(mx);

    // ---- packed label histogram: hA = c0|c1<<16, hB = c2|c3<<16, hC = c4 ----
    int hA = 0, hB = 0, hC = 0;
#define H1(qv)                                  \
    {                                           \
        const int li = (int)(qv);               \
        hA += (li == 0) + ((li == 1) << 16);    \
        hB += (li == 2) + ((li == 3) << 16);    \
        hC += (li == 4);                        \
    }
#define HC(c) H1(qA##c.x) H1(qA##c.y) H1(qA##c.z) H1(qA##c.w)
    CH(HC)
    WAVE_RED(dpp_addi, hA)
    WAVE_RED(dpp_addi, hB)
    WAVE_RED(dpp_addi, hC)
    hA = __builtin_amdgcn_readlane(hA, 63);
    hB = __builtin_amdgcn_readlane(hB, 63);
    hC = __builtin_amdgcn_readlane(hC, 63);

    const int n4 = hC;
    const int n3 = n4 + (hB >> 16);
    const int n2 = n3 + (hB & 0xFFFF);
    const int n1 = n2 + (hA >> 16);
    float idcg = EPSF;
#pragma unroll
    for (int slot = 0; slot < KTOP; ++slot) {
        const int v = (slot < n4) + (slot < n3) + (slot < n2) + (slot < n1);
        idcg = fmaf((float)(1 << v), INVDEN[slot], idcg);
    }

    // ---- packed persistent state: w = z*prod (init z), q labels ----
    const float Cc = ALPHA * LOG2E;
#define WD(c)                                                           \
    v2f wL##c = {(sA##c.x - mn) * Cc, (sA##c.y - mn) * Cc};             \
    v2f wH##c = {(sA##c.z - mn) * Cc, (sA##c.w - mn) * Cc};             \
    const v2f qL##c = {qA##c.x, qA##c.y};                               \
    const v2f qH##c = {qA##c.z, qA##c.w};
    CH(WD)
    float M   = fminf((mx - mn) * Cc, MCLAMP);
    float dcg = EPSF;

#pragma unroll
    for (int k = 0; k < KTOP; ++k) {
        const v2f nM2 = {-M, -M};
#define EDECL(c) v2f eL##c, eH##c;
        CH(EDECL)
        // e = exp2(w - M); volatile pin -> no deletion, no duplication
#define ED(c)                                                       \
    {                                                               \
        const v2f dL = pk_add(wL##c, nM2), dH = pk_add(wH##c, nM2); \
        eL##c.x = __builtin_amdgcn_exp2f(dL.x);                     \
        eL##c.y = __builtin_amdgcn_exp2f(dL.y);                     \
        eH##c.x = __builtin_amdgcn_exp2f(dH.x);                     \
        eH##c.y = __builtin_amdgcn_exp2f(dH.y);                     \
        asm volatile("" : "+v"(eL##c), "+v"(eH##c));                \
    }
        CH(ED)

        v2f accA = {0.0f, 0.0f}, accB = {0.0f, 0.0f};
#define AC(c)                                      \
    accA = pk_add(accA, pk_add(eL##c, eH##c));     \
    accB = pk_fma(qL##c, eL##c,                    \
                  pk_fma(qH##c, eH##c, accB));
        CH(AC)

        // ---- t-trick: e -> t = e*w, w -> 0.9*w. Independent of the
        // reduction -> schedulable into the DPP chain's stall shadow.
        // Post-inv update becomes a single pk_fma per pair. ----
        const v2f c09 = {0.9f, 0.9f};
#define TW(c)                          \
    eL##c = pk_mul(eL##c, wL##c);      \
    wL##c = pk_mul(wL##c, c09);        \
    eH##c = pk_mul(eH##c, wH##c);      \
    wH##c = pk_mul(wH##c, c09);
        CH(TW)

        float se  = accA.x + accA.y;
        float sle = accB.x + accB.y;
        WAVE_RED(dpp_addf, se)
        WAVE_RED(dpp_addf, sle)
        se  = rl63f(se);
        sle = rl63f(sle);

        const float inv = __builtin_amdgcn_rcpf(se);
        dcg = fmaf(__builtin_amdgcn_exp2f(sle * inv), INVDEN[k], dcg);

        // w' = 0.9w - t*inv  ( == w*(0.9 - e*inv), +-1 ulp )
        const v2f niv2 = {-inv, -inv};
#define UP(c)                                  \
    wL##c = pk_fma(eL##c, niv2, wL##c);        \
    wH##c = pk_fma(eH##c, niv2, wH##c);
        CH(UP)
        M *= 0.9f;
    }

    if (lane == 0) {
        const float loss = 1.0f - dcg / idcg;
        if (mode) atomicAdd(out, loss);
        else      ws[row] = loss;
    }
}

__global__ __launch_bounds__(256) void reduce_sum_kernel(
    const float* __restrict__ w, float* __restrict__ out, int n4) {
    __shared__ float sb[4];
    float acc = 0.0f;
    const float4* w4 = (const float4*)w;
    for (int i = threadIdx.x; i < n4; i += 256) {
        const float4 v = w4[i];
        acc += (v.x + v.y) + (v.z + v.w);
    }
#pragma unroll
    for (int o = 32; o; o >>= 1) acc += __shfl_xor(acc, o, 64);
    if ((threadIdx.x & 63) == 0) sb[threadIdx.x >> 6] = acc;
    __syncthreads();
    if (threadIdx.x == 0) out[0] = (sb[0] + sb[1]) + (sb[2] + sb[3]);
}

__global__ void zero_out_kernel(float* out) { out[0] = 0.0f; }

extern "C" void kernel_launch(void* const* d_in, const int* in_sizes, int n_in,
                              void* d_out, int out_size, void* d_ws,
                              size_t ws_size, hipStream_t stream) {
    const float* s     = (const float*)d_in[0];
    const float* label = (const float*)d_in[1];
    float*       out   = (float*)d_out;
    const int    bs    = in_sizes[0] / LL;

    if (ws_size >= (size_t)bs * sizeof(float)) {
        float* w = (float*)d_ws;
        ndcg_loss_kernel<<<bs, THREADS, 0, stream>>>(s, label, w, nullptr, 0);
        reduce_sum_kernel<<<1, 256, 0, stream>>>(w, out, bs / 4);
    } else {
        zero_out_kernel<<<1, 1, 0, stream>>>(out);
        ndcg_loss_kernel<<<bs, THREADS, 0, stream>>>(s, label, nullptr, out, 1);
    }
}

// Round 18
// 78.365 us; speedup vs baseline: 1.2922x; 1.0187x over previous
//
#include <hip/hip_runtime.h>
#include <math.h>

// ListwiseSmoothINDCGKLoss: bs x ll (16384 x 2048) fp32 scores + graded labels
// -> scalar sum(1 - ndcg@10).
//
// Round-18 = round-9 EXACT body (best valid: 75.4 us; 1 row/wave, EPT=32,
// zero LDS/barriers, DPP reductions, volatile-pinned e, packed VOP3P),
// single variable changed: THREADS 256 -> 512 (8 waves/block, one row per
// wave). Evidence: across all correct kernels, 512-thread blocks measured
// the highest occupancy (38-40%, r2/r11) vs 28% @256 and 30% @64. The body
// uses no LDS and no barriers, so block size is purely a scheduling
// container. launch_bounds (512,2) keeps the same VGPR cap (128) under
// which r9's allocator chose 68.
// r17's bundled changes (1-wave blocks + t-trick) are both reverted: 1-wave
// blocks didn't move occupancy (28->30%), t-trick added +32 ops/k for no
// win (VALUBusy 55->62% with worse dur).
//
// Permanently abandoned: UPD-phase exp2 remat (r12/14/15 NaN x3); 2-rows/
// wave (r10 invalid, r11 barrier-taxed, r16 AGPR-shuffle-taxed).
//
// Carried: packed VOP3P fp32 (r9-r11); volatile pin of e after exp2 (r8:
// non-volatile pins get duplicated+remat'd); scale-invariant softmax
// M_k = min(range,118)*0.9^k (no per-k max); NO local arrays (r2-r3);
// IDCG closed form from packed histogram; DPP wave64 reductions; rcp.

typedef float v2f __attribute__((ext_vector_type(2)));

constexpr int LL      = 2048;
constexpr int THREADS = 512;  // 8 waves; wave w handles row blockIdx*8+w
constexpr int RPB     = 8;
constexpr int KTOP    = 10;
constexpr float ALPHA  = 10.0f;
constexpr float EPSF   = 1e-10f;
constexpr float LOG2E  = 1.44269504088896340736f;
constexpr float MCLAMP = 118.0f;

__device__ constexpr float INVDEN[KTOP] = {
    1.0f,                 0.6309297535714574f, 0.5f,                0.43067655807339306f,
    0.38685280723454163f, 0.356207187108022f,  0.3333333333333333f, 0.31546487678572877f,
    0.30102999566398114f, 0.2890648263178878f};

// ---- VOP3P packed fp32 helpers (validated rounds 9-11) ----
__device__ __forceinline__ v2f pk_add(v2f a, v2f b) {
    v2f d; asm("v_pk_add_f32 %0, %1, %2" : "=v"(d) : "v"(a), "v"(b)); return d;
}
__device__ __forceinline__ v2f pk_mul(v2f a, v2f b) {
    v2f d; asm("v_pk_mul_f32 %0, %1, %2" : "=v"(d) : "v"(a), "v"(b)); return d;
}
__device__ __forceinline__ v2f pk_fma(v2f a, v2f b, v2f c) {
    v2f d; asm("v_pk_fma_f32 %0, %1, %2, %3" : "=v"(d) : "v"(a), "v"(b), "v"(c)); return d;
}

// ---- DPP wave64 reductions (result lands in lane 63) ----
template <int CTRL>
__device__ __forceinline__ float dpp_addf(float v) {
    return v + __int_as_float(__builtin_amdgcn_update_dpp(
                   0, __float_as_int(v), CTRL, 0xF, 0xF, false));
}
template <int CTRL>
__device__ __forceinline__ float dpp_minf(float v) {
    return fminf(v, __int_as_float(__builtin_amdgcn_update_dpp(
                        0x7F800000, __float_as_int(v), CTRL, 0xF, 0xF, false)));
}
template <int CTRL>
__device__ __forceinline__ float dpp_maxf(float v) {
    return fmaxf(v, __int_as_float(__builtin_amdgcn_update_dpp(
                        (int)0xFF800000, __float_as_int(v), CTRL, 0xF, 0xF, false)));
}
template <int CTRL>
__device__ __forceinline__ int dpp_addi(int v) {
    return v + __builtin_amdgcn_update_dpp(0, v, CTRL, 0xF, 0xF, false);
}

// row_shr:1,2,4,8 then row_bcast:15, row_bcast:31
#define WAVE_RED(OP, v)                                                     \
    v = OP<0x111>(v); v = OP<0x112>(v); v = OP<0x114>(v); v = OP<0x118>(v); \
    v = OP<0x142>(v); v = OP<0x143>(v);

__device__ __forceinline__ float rl63f(float v) {
    return __int_as_float(__builtin_amdgcn_readlane(__float_as_int(v), 63));
}

// chunk expander: 8 chunks x 4 scalars = 32 elements per lane
#define CH(F) F(0) F(1) F(2) F(3) F(4) F(5) F(6) F(7)

__global__ __launch_bounds__(THREADS, 2) void ndcg_loss_kernel(
    const float* __restrict__ s, const float* __restrict__ label,
    float* __restrict__ ws, float* __restrict__ out, int mode) {
    const int    lane = threadIdx.x & 63;
    const int    wave = threadIdx.x >> 6;
    const size_t row  = (size_t)blockIdx.x * RPB + wave;

    const float4* sp = (const float4*)(s + row * (size_t)LL);
    const float4* lp = (const float4*)(label + row * (size_t)LL);

    // coalesced loads: chunk c = 1 KB contiguous (64 lanes x 16 B)
#define LOADS(c) const float4 sA##c = sp[(c) * 64 + lane];
    CH(LOADS)
#define LOADL(c) const float4 qA##c = lp[(c) * 64 + lane];
    CH(LOADL)

    // ---- row min / max ----
    float mn = sA0.x, mx = sA0.x;
#define MM(c)                                                                \
    mn = fminf(mn, fminf(fminf(sA##c.x, sA##c.y), fminf(sA##c.z, sA##c.w))); \
    mx = fmaxf(mx, fmaxf(fmaxf(sA##c.x, sA##c.y), fmaxf(sA##c.z, sA##c.w)));
    CH(MM)
    WAVE_RED(dpp_minf, mn)
    WAVE_RED(dpp_maxf, mx)
    mn = rl63f(mn);
    mx = rl63f(mx);

    // ---- packed label histogram: hA = c0|c1<<16, hB = c2|c3<<16, hC = c4 ----
    int hA = 0, hB = 0, hC = 0;
#define H1(qv)                                  \
    {                                           \
        const int li = (int)(qv);               \
        hA += (li == 0) + ((li == 1) << 16);    \
        hB += (li == 2) + ((li == 3) << 16);    \
        hC += (li == 4);                        \
    }
#define HC(c) H1(qA##c.x) H1(qA##c.y) H1(qA##c.z) H1(qA##c.w)
    CH(HC)
    WAVE_RED(dpp_addi, hA)
    WAVE_RED(dpp_addi, hB)
    WAVE_RED(dpp_addi, hC)
    hA = __builtin_amdgcn_readlane(hA, 63);
    hB = __builtin_amdgcn_readlane(hB, 63);
    hC = __builtin_amdgcn_readlane(hC, 63);

    const int n4 = hC;
    const int n3 = n4 + (hB >> 16);
    const int n2 = n3 + (hB & 0xFFFF);
    const int n1 = n2 + (hA >> 16);
    float idcg = EPSF;
#pragma unroll
    for (int slot = 0; slot < KTOP; ++slot) {
        const int v = (slot < n4) + (slot < n3) + (slot < n2) + (slot < n1);
        idcg = fmaf((float)(1 << v), INVDEN[slot], idcg);
    }

    // ---- packed persistent state: w = z*prod (init z), q labels ----
    const float Cc = ALPHA * LOG2E;
#define WD(c)                                                           \
    v2f wL##c = {(sA##c.x - mn) * Cc, (sA##c.y - mn) * Cc};             \
    v2f wH##c = {(sA##c.z - mn) * Cc, (sA##c.w - mn) * Cc};             \
    const v2f qL##c = {qA##c.x, qA##c.y};                               \
    const v2f qH##c = {qA##c.z, qA##c.w};
    CH(WD)
    float M   = fminf((mx - mn) * Cc, MCLAMP);
    float dcg = EPSF;

#pragma unroll
    for (int k = 0; k < KTOP; ++k) {
        const v2f nM2 = {-M, -M};
#define EDECL(c) v2f eL##c, eH##c;
        CH(EDECL)
        // e = exp2(w - M); volatile pin -> no deletion, no duplication
#define ED(c)                                                       \
    {                                                               \
        const v2f dL = pk_add(wL##c, nM2), dH = pk_add(wH##c, nM2); \
        eL##c.x = __builtin_amdgcn_exp2f(dL.x);                     \
        eL##c.y = __builtin_amdgcn_exp2f(dL.y);                     \
        eH##c.x = __builtin_amdgcn_exp2f(dH.x);                     \
        eH##c.y = __builtin_amdgcn_exp2f(dH.y);                     \
        asm volatile("" : "+v"(eL##c), "+v"(eH##c));                \
    }
        CH(ED)

        v2f accA = {0.0f, 0.0f}, accB = {0.0f, 0.0f};
#define AC(c)                                      \
    accA = pk_add(accA, pk_add(eL##c, eH##c));     \
    accB = pk_fma(qL##c, eL##c,                    \
                  pk_fma(qH##c, eH##c, accB));
        CH(AC)
        float se  = accA.x + accA.y;
        float sle = accB.x + accB.y;
        WAVE_RED(dpp_addf, se)
        WAVE_RED(dpp_addf, sle)
        se  = rl63f(se);
        sle = rl63f(sle);

        const float inv = __builtin_amdgcn_rcpf(se);
        dcg = fmaf(__builtin_amdgcn_exp2f(sle * inv), INVDEN[k], dcg);

        // w' = w * (0.9 - e*inv)   [prod update folded into w]
        const v2f niv2 = {-inv, -inv};
        const v2f c09  = {0.9f, 0.9f};
#define UP(c)                                        \
    wL##c = pk_mul(wL##c, pk_fma(eL##c, niv2, c09)); \
    wH##c = pk_mul(wH##c, pk_fma(eH##c, niv2, c09));
        CH(UP)
        M *= 0.9f;
    }

    if (lane == 0) {
        const float loss = 1.0f - dcg / idcg;
        if (mode) atomicAdd(out, loss);
        else      ws[row] = loss;
    }
}

__global__ __launch_bounds__(256) void reduce_sum_kernel(
    const float* __restrict__ w, float* __restrict__ out, int n4) {
    __shared__ float sb[4];
    float acc = 0.0f;
    const float4* w4 = (const float4*)w;
    for (int i = threadIdx.x; i < n4; i += 256) {
        const float4 v = w4[i];
        acc += (v.x + v.y) + (v.z + v.w);
    }
#pragma unroll
    for (int o = 32; o; o >>= 1) acc += __shfl_xor(acc, o, 64);
    if ((threadIdx.x & 63) == 0) sb[threadIdx.x >> 6] = acc;
    __syncthreads();
    if (threadIdx.x == 0) out[0] = (sb[0] + sb[1]) + (sb[2] + sb[3]);
}

__global__ void zero_out_kernel(float* out) { out[0] = 0.0f; }

extern "C" void kernel_launch(void* const* d_in, const int* in_sizes, int n_in,
                              void* d_out, int out_size, void* d_ws,
                              size_t ws_size, hipStream_t stream) {
    const float* s     = (const float*)d_in[0];
    const float* label = (const float*)d_in[1];
    float*       out   = (float*)d_out;
    const int    bs    = in_sizes[0] / LL;

    if ((bs % RPB) == 0 && ws_size >= (size_t)bs * sizeof(float)) {
        float* w = (float*)d_ws;
        ndcg_loss_kernel<<<bs / RPB, THREADS, 0, stream>>>(s, label, w, nullptr, 0);
        reduce_sum_kernel<<<1, 256, 0, stream>>>(w, out, bs / 4);
    } else {
        zero_out_kernel<<<1, 1, 0, stream>>>(out);
        ndcg_loss_kernel<<<bs / RPB, THREADS, 0, stream>>>(s, label, nullptr, out, 1);
    }
}